// Round 5
// baseline (565.215 us; speedup 1.0000x reference)
//
#include <hip/hip_runtime.h>
#include <hip/hip_bf16.h>
#include <math.h>

#define R_CNT   20000
#define L_CNT   30
#define D_CNT   200
#define A_CNT   32
#define B_CNT   4096
#define NNZ_CNT 65536
#define AVG_RATING 3.8f

#define WAVES_TOTAL 10000   // 2500 blocks x 4 waves; each wave does 2 reviews

// ---- d_out layout (floats) ----
#define OUT_OBJ  0
#define OUT_RL   1
#define OUT_AB   (1 + B_CNT)               // 4097
#define OUT_PRED (OUT_AB + 2*R_CNT)        // 44097
#define OUT_UA   (OUT_PRED + B_CNT)        // 48193
#define OUT_IA   (OUT_UA + B_CNT*A_CNT)    // 179265

// ---- ws layout (bytes) ----
#define WS_DBL    0        // double[4]: 0=J_sum, 1=S_sum, 2=rating_sum
#define WS_ULOSS  32       // float
#define WS_MODE   36       // int (1 => indices are int64 in memory)
#define WS_FMLIN  64       // float[4096]
#define WS_PT     16448    // float[R*32]
#define WS_V      2576448  // float[R*200]
#define WS_TT     18576448 // float[32*200]  T_w transposed: T_t[a][d]

// Block-wide reduction of 4 channels across 256 threads (4 waves of 64).
__device__ __forceinline__ float4 blk_reduce4(float4 v, float4* scratch) {
    __syncthreads();
    #pragma unroll
    for (int o = 32; o >= 1; o >>= 1) {
        v.x += __shfl_xor(v.x, o);
        v.y += __shfl_xor(v.y, o);
        v.z += __shfl_xor(v.z, o);
        v.w += __shfl_xor(v.w, o);
    }
    int w = threadIdx.x >> 6;
    if ((threadIdx.x & 63) == 0) scratch[w] = v;
    __syncthreads();
    float4 t0 = scratch[0], t1 = scratch[1], t2 = scratch[2], t3 = scratch[3];
    return make_float4(t0.x + t1.x + t2.x + t3.x,
                       t0.y + t1.y + t2.y + t3.y,
                       t0.z + t1.z + t2.z + t3.z,
                       t0.w + t1.w + t2.w + t3.w);
}

__device__ __forceinline__ float wsum(float v) {
    #pragma unroll
    for (int o = 1; o < 64; o <<= 1) v += __shfl_xor(v, o);
    return v;
}

// ---- K_init: zero accumulators, detect index dtype, transpose T_w ----
__global__ __launch_bounds__(256) void k_init(float* __restrict__ out,
                                              double* __restrict__ dbl,
                                              float* __restrict__ uloss,
                                              int* __restrict__ mode,
                                              const int* __restrict__ u_idx,
                                              const float* __restrict__ T_w,
                                              float* __restrict__ T_t) {
    int gid = blockIdx.x * 256 + threadIdx.x;
    if (gid < 2 * B_CNT * A_CNT) out[OUT_UA + gid] = 0.f;
    if (gid < A_CNT * D_CNT) {               // T_t[a][d] = T_w[d][a]
        int a = gid / D_CNT, d = gid - a * D_CNT;
        T_t[gid] = T_w[d * A_CNT + a];
    }
    if (gid == 0) {
        dbl[0] = 0.0; dbl[1] = 0.0; dbl[2] = 0.0;
        *uloss = 0.f;
        int m = 1;
        for (int i = 1; i < 256; i += 2) if (u_idx[i] != 0) { m = 0; break; }
        *mode = m;
    }
}

// ---- K_uloss: orthogonality regularizer on T_w columns (tiny, 1 block) ----
__global__ __launch_bounds__(256) void k_uloss(const float* __restrict__ T_w,
                                               float* __restrict__ uloss) {
    __shared__ float tn[32];
    __shared__ float4 red4[4];
    int tid = threadIdx.x;
    int a = tid >> 3, k = tid & 7;
    float p = 0.f;
    for (int d = k; d < D_CNT; d += 8) { float t = T_w[d*32 + a]; p = fmaf(t, t, p); }
    p += __shfl_xor(p, 1); p += __shfl_xor(p, 2); p += __shfl_xor(p, 4);
    if (k == 0) tn[a] = fmaxf(sqrtf(p), 1e-12f);
    __syncthreads();
    float local = 0.f;
    for (int t = 0; t < 4; t++) {
        int e = tid + 256 * t;
        int i = e >> 5, j = e & 31;
        float s = 0.f;
        for (int d = 0; d < D_CNT; d++) s = fmaf(T_w[d*32 + i], T_w[d*32 + j], s);
        float g = s / (tn[i] * tn[j]);
        float diff = g - ((i == j) ? 1.f : 0.f);
        local += diff * diff;
    }
    float4 tot = blk_reduce4(make_float4(local, 0.f, 0.f, 0.f), red4);
    if (tid == 0) *uloss = tot.x / 1024.f;
}

// ---- K_vgemm: V = Y_s (R x 200) @ M_w (200 x 200) ----
__global__ __launch_bounds__(256) void k_vgemm(const float* __restrict__ y_s,
                                               const float* __restrict__ M_w,
                                               float* __restrict__ V) {
    __shared__ __align__(16) float Msh[25 * 260];
    __shared__ __align__(16) float Ysh[25 * 68];
    int tid = threadIdx.x;
    int r0 = blockIdx.x * 64;
    int dg = tid & 31, rg = tid >> 5;
    float acc[8][8];
    #pragma unroll
    for (int i = 0; i < 8; i++)
        #pragma unroll
        for (int j = 0; j < 8; j++) acc[i][j] = 0.f;

    for (int e0 = 0; e0 < D_CNT; e0 += 25) {
        __syncthreads();
        for (int idx = tid; idx < 25 * 256; idx += 256) {
            int ee = idx >> 8, d = idx & 255;
            Msh[ee * 260 + d] = (d < D_CNT) ? M_w[(e0 + ee) * D_CNT + d] : 0.f;
        }
        for (int idx = tid; idx < 25 * 64; idx += 256) {
            int rr = idx / 25, ee = idx - rr * 25;
            int row = r0 + rr;
            Ysh[ee * 68 + rr] = (row < R_CNT) ? y_s[row * D_CNT + e0 + ee] : 0.f;
        }
        __syncthreads();
        for (int ee = 0; ee < 25; ee++) {
            const float4 ya = *(const float4*)&Ysh[ee * 68 + rg * 8];
            const float4 yb = *(const float4*)&Ysh[ee * 68 + rg * 8 + 4];
            const float4 ma = *(const float4*)&Msh[ee * 260 + dg * 8];
            const float4 mb = *(const float4*)&Msh[ee * 260 + dg * 8 + 4];
            float ys[8] = {ya.x, ya.y, ya.z, ya.w, yb.x, yb.y, yb.z, yb.w};
            float ms[8] = {ma.x, ma.y, ma.z, ma.w, mb.x, mb.y, mb.z, mb.w};
            #pragma unroll
            for (int i = 0; i < 8; i++)
                #pragma unroll
                for (int j = 0; j < 8; j++)
                    acc[i][j] = fmaf(ys[i], ms[j], acc[i][j]);
        }
    }
    if (dg < 25) {
        #pragma unroll
        for (int i = 0; i < 8; i++) {
            int row = r0 + rg * 8 + i;
            if (row < R_CNT) {
                *(float4*)&V[row * D_CNT + dg * 8]     = make_float4(acc[i][0], acc[i][1], acc[i][2], acc[i][3]);
                *(float4*)&V[row * D_CNT + dg * 8 + 4] = make_float4(acc[i][4], acc[i][5], acc[i][6], acc[i][7]);
            }
        }
    }
}

// ---- K_main: wave-per-review, zero LDS, zero barriers, online softmax ----
// Lane j<50 owns d-slice [4j..4j+3] (one float4). e_w streamed once; dx ->
// softmax -> z_s fused flash-style; all cross-lane via 64-lane shuffles.
__global__ __launch_bounds__(256) void k_main(
    const float* __restrict__ e_w, const float* __restrict__ z_n,
    const float* __restrict__ W_w, const float* __restrict__ W_b,
    const float* __restrict__ T_t, const float* __restrict__ T_b,
    const float* __restrict__ V, float* __restrict__ p_t,
    float* __restrict__ out, double* __restrict__ j_sum) {
    const int lane = threadIdx.x & 63;
    const int wave = (blockIdx.x * 256 + threadIdx.x) >> 6;  // 0..9999
    const bool act = lane < 50;
    const int dl = act ? lane : 0;

    const float wb = (lane < 32) ? W_b[lane] : 0.f;
    float4 tb4 = ((const float4*)T_b)[dl];
    if (!act) tb4 = make_float4(0.f, 0.f, 0.f, 0.f);

    double jloc = 0.0;

    #pragma unroll
    for (int it = 0; it < 2; ++it) {
        const int r = wave + it * WAVES_TOTAL;
        const float4* ew4 = (const float4*)(e_w + (size_t)r * (L_CNT * D_CNT));
        float4 v4 = ((const float4*)(V + (size_t)r * D_CNT))[dl];
        float4 za = ((const float4*)(z_n + (size_t)(2 * r) * D_CNT))[dl];
        float4 zb = ((const float4*)(z_n + (size_t)(2 * r + 1) * D_CNT))[dl];

        // online softmax over L=30 rows, batch-2, depth-1 prefetch
        float m = -3.0e38f, s = 0.f;
        float4 zs = make_float4(0.f, 0.f, 0.f, 0.f);
        float4 e0 = ew4[dl];
        float4 e1 = ew4[50 + dl];
        #pragma unroll
        for (int l = 0; l < L_CNT; l += 2) {
            float4 n0 = e0, n1 = e1;
            if (l + 2 < L_CNT) {
                n0 = ew4[(l + 2) * 50 + dl];
                n1 = ew4[(l + 3) * 50 + dl];
            }
            float p0 = act ? (e0.x*v4.x + e0.y*v4.y + e0.z*v4.z + e0.w*v4.w) : 0.f;
            float p1 = act ? (e1.x*v4.x + e1.y*v4.y + e1.z*v4.z + e1.w*v4.w) : 0.f;
            #pragma unroll
            for (int o = 1; o < 64; o <<= 1) {
                p0 += __shfl_xor(p0, o);
                p1 += __shfl_xor(p1, o);
            }
            float nm = fmaxf(m, fmaxf(p0, p1));
            float sc = __expf(m - nm);
            float w0 = __expf(p0 - nm);
            float w1 = __expf(p1 - nm);
            s = s * sc + w0 + w1;
            zs.x = zs.x * sc + w0 * e0.x + w1 * e1.x;
            zs.y = zs.y * sc + w0 * e0.y + w1 * e1.y;
            zs.z = zs.z * sc + w0 * e0.z + w1 * e1.z;
            zs.w = zs.w * sc + w0 * e0.w + w1 * e1.w;
            m = nm;
            e0 = n0; e1 = n1;
        }
        const float inv = 1.f / s;
        zs.x *= inv; zs.y *= inv; zs.z *= inv; zs.w *= inv;

        // p_t[a] = z_s . W_w[a,:] + W_b[a]; lane a keeps its value
        float ptl = 0.f;
        #pragma unroll
        for (int a = 0; a < A_CNT; ++a) {
            float4 ww = ((const float4*)(W_w + a * D_CNT))[dl];
            float q = act ? (zs.x*ww.x + zs.y*ww.y + zs.z*ww.z + zs.w*ww.w) : 0.f;
            q = wsum(q);
            if (lane == a) ptl = q + wb;
        }
        if (lane < A_CNT) p_t[(size_t)r * A_CNT + lane] = ptl;

        // r_s slice via transposed T (coalesced): r4 = T_b + sum_a pt[a]*T_t[a,:]
        float4 r4 = tb4;
        #pragma unroll
        for (int a = 0; a < A_CNT; ++a) {
            float pa = __shfl(ptl, a);
            float4 tt = ((const float4*)(T_t + a * D_CNT))[dl];
            r4.x = fmaf(pa, tt.x, r4.x);
            r4.y = fmaf(pa, tt.y, r4.y);
            r4.z = fmaf(pa, tt.z, r4.z);
            r4.w = fmaf(pa, tt.w, r4.w);
        }

        // 7-channel cosine-loss partials (act-guarded), single shuffle reduce
        float rr = 0.f, rz = 0.f, zz = 0.f, n00 = 0.f, n0r = 0.f, n11 = 0.f, n1r = 0.f;
        if (act) {
            rr  = r4.x*r4.x + r4.y*r4.y + r4.z*r4.z + r4.w*r4.w;
            rz  = r4.x*zs.x + r4.y*zs.y + r4.z*zs.z + r4.w*zs.w;
            zz  = zs.x*zs.x + zs.y*zs.y + zs.z*zs.z + zs.w*zs.w;
            n00 = za.x*za.x + za.y*za.y + za.z*za.z + za.w*za.w;
            n0r = za.x*r4.x + za.y*r4.y + za.z*r4.z + za.w*r4.w;
            n11 = zb.x*zb.x + zb.y*zb.y + zb.z*zb.z + zb.w*zb.w;
            n1r = zb.x*r4.x + zb.y*r4.y + zb.z*r4.z + zb.w*r4.w;
        }
        #pragma unroll
        for (int o = 1; o < 64; o <<= 1) {
            rr  += __shfl_xor(rr, o);  rz  += __shfl_xor(rz, o);
            zz  += __shfl_xor(zz, o);  n00 += __shfl_xor(n00, o);
            n0r += __shfl_xor(n0r, o); n11 += __shfl_xor(n11, o);
            n1r += __shfl_xor(n1r, o);
        }
        if (lane == 0) {
            float nr = fmaxf(sqrtf(rr), 1e-12f);
            float nz = fmaxf(sqrtf(zz), 1e-12f);
            float c1  = rz  / (nr * nz);
            float c20 = n0r / (fmaxf(sqrtf(n00), 1e-12f) * nr);
            float c21 = n1r / (fmaxf(sqrtf(n11), 1e-12f) * nr);
            float l0 = fmaxf(0.f, 1.f - (c1 - c20));
            float l1 = fmaxf(0.f, 1.f - (c1 - c21));
            out[OUT_AB + 2 * r]     = l0;
            out[OUT_AB + 2 * r + 1] = l1;
            jloc += (double)l0 + (double)l1;
        }
    }
    if (lane == 0) atomicAdd(j_sum, jloc);
}

// ---- K_scatter: user/item aspect segment sums via atomics ----
__global__ __launch_bounds__(256) void k_scatter(const int* __restrict__ u_idx,
                                                 const int* __restrict__ i_idx,
                                                 const float* __restrict__ u_val,
                                                 const float* __restrict__ i_val,
                                                 const float* __restrict__ p_t,
                                                 const int* __restrict__ mode,
                                                 float* __restrict__ out) {
    long long gid = (long long)blockIdx.x * 256 + threadIdx.x;
    const long long HALF = (long long)NNZ_CNT * 32;
    int is_item = gid >= HALF;
    long long rem = gid - (is_item ? HALF : 0);
    int k = (int)(rem >> 5), a = (int)(rem & 31);
    const int* idx = is_item ? i_idx : u_idx;
    const float* val = is_item ? i_val : u_val;
    int m64 = *mode;
    int row, col;
    if (m64) { row = idx[2 * k]; col = idx[2 * (NNZ_CNT + k)]; }
    else     { row = idx[k];     col = idx[NNZ_CNT + k]; }
    float v = p_t[col * 32 + a] * val[k];
    float* base = out + (is_item ? OUT_IA : OUT_UA);
    atomicAdd(&base[row * 32 + a], v);
}

// ---- K_fm: factorization machine per-b terms + global scalar S ----
__global__ __launch_bounds__(256) void k_fm(const float* __restrict__ out,
                                            const float* __restrict__ fc_w,
                                            const float* __restrict__ fc_b,
                                            const float* __restrict__ fm_V,
                                            float* __restrict__ fm_lin,
                                            double* __restrict__ s_sum) {
    int tid = threadIdx.x;
    int a = tid & 31;
    int b = blockIdx.x * 8 + (tid >> 5);
    float ua = out[OUT_UA + b * 32 + a];
    float ia = out[OUT_IA + b * 32 + a];
    float oe = ua * ia;
    float oe2 = oe * oe;
    float lin = oe * fc_w[a];
    #pragma unroll
    for (int o = 1; o < 32; o <<= 1) lin += __shfl_xor(lin, o);
    float part = 0.f;
    #pragma unroll
    for (int j = 0; j < 10; j++) {
        float v = fm_V[a * 10 + j];
        float s1 = oe * v;
        float s2 = oe2 * v * v;
        #pragma unroll
        for (int o = 1; o < 32; o <<= 1) { s1 += __shfl_xor(s1, o); s2 += __shfl_xor(s2, o); }
        part += s1 * s1 - s2;
    }
    if (a == 0) {
        fm_lin[b] = lin + fc_b[0];
        atomicAdd(s_sum, 0.5 * (double)part);
    }
}

// ---- K_pred: predictions + rating losses + rating_sum ----
__global__ __launch_bounds__(256) void k_pred(const float* __restrict__ label,
                                              const float* __restrict__ fm_lin,
                                              const double* __restrict__ s_sum,
                                              float* __restrict__ out,
                                              double* __restrict__ r_sum) {
    __shared__ float4 red4[4];
    int b = blockIdx.x * 256 + threadIdx.x;
    float S = (float)(*s_sum);
    float pred = fm_lin[b] + S + AVG_RATING;
    float d = pred - label[b];
    float rl = d * d;
    out[OUT_PRED + b] = pred;
    out[OUT_RL + b] = rl;
    float4 t = blk_reduce4(make_float4(rl, 0.f, 0.f, 0.f), red4);
    if (threadIdx.x == 0) atomicAdd(r_sum, (double)t.x);
}

// ---- K_final: assemble scalar objective ----
__global__ void k_final(const double* __restrict__ dbl,
                        const float* __restrict__ uloss,
                        float* __restrict__ out) {
    if (threadIdx.x == 0) {
        double J = dbl[0] / (2.0 * R_CNT);
        double RL = dbl[2] / (double)B_CNT;
        out[OUT_OBJ] = (float)(RL + (double)(*uloss) + J);
    }
}

extern "C" void kernel_launch(void* const* d_in, const int* in_sizes, int n_in,
                              void* d_out, int out_size, void* d_ws, size_t ws_size,
                              hipStream_t stream) {
    const float* e_w   = (const float*)d_in[0];
    const float* y_s   = (const float*)d_in[1];
    const float* z_n   = (const float*)d_in[2];
    const float* label = (const float*)d_in[3];
    const float* u_val = (const float*)d_in[4];
    const float* i_val = (const float*)d_in[5];
    const float* M_w   = (const float*)d_in[6];
    const float* W_w   = (const float*)d_in[8];
    const float* W_b   = (const float*)d_in[9];
    const float* T_w   = (const float*)d_in[10];
    const float* T_b   = (const float*)d_in[11];
    const float* fc_w  = (const float*)d_in[12];
    const float* fc_b  = (const float*)d_in[13];
    const float* fm_V  = (const float*)d_in[14];
    const int*   u_idx = (const int*)d_in[15];
    const int*   i_idx = (const int*)d_in[16];

    float* out = (float*)d_out;
    char* ws = (char*)d_ws;
    double* dbl   = (double*)(ws + WS_DBL);
    float* uloss  = (float*)(ws + WS_ULOSS);
    int* mode     = (int*)(ws + WS_MODE);
    float* fm_lin = (float*)(ws + WS_FMLIN);
    float* p_t    = (float*)(ws + WS_PT);
    float* V      = (float*)(ws + WS_V);
    float* T_t    = (float*)(ws + WS_TT);

    k_init<<<(2 * B_CNT * A_CNT) / 256, 256, 0, stream>>>(out, dbl, uloss, mode,
                                                          u_idx, T_w, T_t);
    k_uloss<<<1, 256, 0, stream>>>(T_w, uloss);
    k_vgemm<<<(R_CNT + 63) / 64, 256, 0, stream>>>(y_s, M_w, V);
    k_main<<<WAVES_TOTAL / 4, 256, 0, stream>>>(e_w, z_n, W_w, W_b, T_t, T_b,
                                                V, p_t, out, &dbl[0]);
    k_scatter<<<(2 * NNZ_CNT * 32) / 256, 256, 0, stream>>>(u_idx, i_idx, u_val, i_val,
                                                            p_t, mode, out);
    k_fm<<<B_CNT / 8, 256, 0, stream>>>(out, fc_w, fc_b, fm_V, fm_lin, &dbl[1]);
    k_pred<<<B_CNT / 256, 256, 0, stream>>>(label, fm_lin, &dbl[1], out, &dbl[2]);
    k_final<<<1, 64, 0, stream>>>(dbl, uloss, out);
}

// Round 6
// 550.940 us; speedup vs baseline: 1.0259x; 1.0259x over previous
//
#include <hip/hip_runtime.h>
#include <hip/hip_bf16.h>
#include <math.h>

#define R_CNT   20000
#define L_CNT   30
#define D_CNT   200
#define A_CNT   32
#define B_CNT   4096
#define NNZ_CNT 65536
#define AVG_RATING 3.8f

#define GRID_MAIN 1536   // persistent blocks; 6 blocks/CU by LDS

// ---- d_out layout (floats) ----
#define OUT_OBJ  0
#define OUT_RL   1
#define OUT_AB   (1 + B_CNT)               // 4097
#define OUT_PRED (OUT_AB + 2*R_CNT)        // 44097
#define OUT_UA   (OUT_PRED + B_CNT)        // 48193
#define OUT_IA   (OUT_UA + B_CNT*A_CNT)    // 179265

// ---- ws layout (bytes) ----
#define WS_DBL    0         // double[4]: [2]=rating_sum
#define WS_MODE   32        // int (1 => indices are int64 in memory)
#define WS_FMLIN  64        // float[4096]
#define WS_PT     16448     // float[R*32]
#define WS_V      2576448   // float[R*200] -> ends 18576448
#define WS_JPART  18576448  // double[1536]
#define WS_SPART  18588736  // double[512]
#define WS_UPART  18592832  // float[32]

// Block-wide reduction of 4 channels across 256 threads (4 waves of 64).
__device__ __forceinline__ float4 blk_reduce4(float4 v, float4* scratch) {
    __syncthreads();
    #pragma unroll
    for (int o = 32; o >= 1; o >>= 1) {
        v.x += __shfl_xor(v.x, o);
        v.y += __shfl_xor(v.y, o);
        v.z += __shfl_xor(v.z, o);
        v.w += __shfl_xor(v.w, o);
    }
    int w = threadIdx.x >> 6;
    if ((threadIdx.x & 63) == 0) scratch[w] = v;
    __syncthreads();
    float4 t0 = scratch[0], t1 = scratch[1], t2 = scratch[2], t3 = scratch[3];
    return make_float4(t0.x + t1.x + t2.x + t3.x,
                       t0.y + t1.y + t2.y + t3.y,
                       t0.z + t1.z + t2.z + t3.z,
                       t0.w + t1.w + t2.w + t3.w);
}

// ---- K_init: zero accumulators + aspect outputs, detect index dtype ----
__global__ __launch_bounds__(256) void k_init(float* __restrict__ out,
                                              double* __restrict__ dbl,
                                              int* __restrict__ mode,
                                              const int* __restrict__ u_idx) {
    int gid = blockIdx.x * 256 + threadIdx.x;
    if (gid < 2 * B_CNT * A_CNT) out[OUT_UA + gid] = 0.f;
    if (gid == 0) {
        dbl[0] = 0.0; dbl[1] = 0.0; dbl[2] = 0.0;
        int m = 1;
        for (int i = 1; i < 256; i += 2) if (u_idx[i] != 0) { m = 0; break; }
        *mode = m;
    }
}

// ---- K_uloss: orthogonality regularizer, one G-row per block (32 blocks) ----
__global__ __launch_bounds__(256) void k_uloss(const float* __restrict__ T_w,
                                               float* __restrict__ upart) {
    __shared__ __align__(16) float Tsh[D_CNT * 32];  // same layout as T_w
    __shared__ float tn[32];
    __shared__ float4 red4[4];
    int tid = threadIdx.x;
    for (int idx = tid; idx < 1600; idx += 256)
        ((float4*)Tsh)[idx] = ((const float4*)T_w)[idx];
    __syncthreads();
    int a = tid >> 3, k = tid & 7;
    float p = 0.f;
    #pragma unroll
    for (int j = 0; j < 25; ++j) { float t = Tsh[(k + 8*j)*32 + a]; p = fmaf(t, t, p); }
    p += __shfl_xor(p, 1); p += __shfl_xor(p, 2); p += __shfl_xor(p, 4);
    if (k == 0) tn[a] = fmaxf(sqrtf(p), 1e-12f);
    __syncthreads();
    const int i = blockIdx.x;   // G row
    float s = 0.f;
    #pragma unroll
    for (int j = 0; j < 25; ++j)
        s = fmaf(Tsh[(k + 8*j)*32 + i], Tsh[(k + 8*j)*32 + a], s);
    s += __shfl_xor(s, 1); s += __shfl_xor(s, 2); s += __shfl_xor(s, 4);
    float part = 0.f;
    if (k == 0) {
        float g = s / (tn[i] * tn[a]);
        float diff = g - ((i == a) ? 1.f : 0.f);
        part = diff * diff;
    }
    float4 tot = blk_reduce4(make_float4(part, 0.f, 0.f, 0.f), red4);
    if (tid == 0) upart[i] = tot.x;
}

// ---- K_vgemm: V = Y_s (R x 200) @ M_w (200 x 200) ----
__global__ __launch_bounds__(256) void k_vgemm(const float* __restrict__ y_s,
                                               const float* __restrict__ M_w,
                                               float* __restrict__ V) {
    __shared__ __align__(16) float Msh[25 * 260];
    __shared__ __align__(16) float Ysh[25 * 68];
    int tid = threadIdx.x;
    int r0 = blockIdx.x * 64;
    int dg = tid & 31, rg = tid >> 5;
    float acc[8][8];
    #pragma unroll
    for (int i = 0; i < 8; i++)
        #pragma unroll
        for (int j = 0; j < 8; j++) acc[i][j] = 0.f;

    for (int e0 = 0; e0 < D_CNT; e0 += 25) {
        __syncthreads();
        for (int idx = tid; idx < 25 * 256; idx += 256) {
            int ee = idx >> 8, d = idx & 255;
            Msh[ee * 260 + d] = (d < D_CNT) ? M_w[(e0 + ee) * D_CNT + d] : 0.f;
        }
        for (int idx = tid; idx < 25 * 64; idx += 256) {
            int rr = idx / 25, ee = idx - rr * 25;
            int row = r0 + rr;
            Ysh[ee * 68 + rr] = (row < R_CNT) ? y_s[row * D_CNT + e0 + ee] : 0.f;
        }
        __syncthreads();
        for (int ee = 0; ee < 25; ee++) {
            const float4 ya = *(const float4*)&Ysh[ee * 68 + rg * 8];
            const float4 yb = *(const float4*)&Ysh[ee * 68 + rg * 8 + 4];
            const float4 ma = *(const float4*)&Msh[ee * 260 + dg * 8];
            const float4 mb = *(const float4*)&Msh[ee * 260 + dg * 8 + 4];
            float ys[8] = {ya.x, ya.y, ya.z, ya.w, yb.x, yb.y, yb.z, yb.w};
            float ms[8] = {ma.x, ma.y, ma.z, ma.w, mb.x, mb.y, mb.z, mb.w};
            #pragma unroll
            for (int i = 0; i < 8; i++)
                #pragma unroll
                for (int j = 0; j < 8; j++)
                    acc[i][j] = fmaf(ys[i], ms[j], acc[i][j]);
        }
    }
    if (dg < 25) {
        #pragma unroll
        for (int i = 0; i < 8; i++) {
            int row = r0 + rg * 8 + i;
            if (row < R_CNT) {
                *(float4*)&V[row * D_CNT + dg * 8]     = make_float4(acc[i][0], acc[i][1], acc[i][2], acc[i][3]);
                *(float4*)&V[row * D_CNT + dg * 8 + 4] = make_float4(acc[i][4], acc[i][5], acc[i][6], acc[i][7]);
            }
        }
    }
}

// ---- K_main: persistent blocks, reg-prefetch double buffering, no atomics ----
// Per review: stage(prefetched) -> dx -> softmax -> z_s -> p_t(+stage write)
// -> fused loss. 5 barriers/review; next review's 24KB is in flight during
// the whole compute phase, so HBM stays busy.
__global__ __launch_bounds__(256, 6) void k_main(
    const float* __restrict__ e_w, const float* __restrict__ z_n,
    const float* __restrict__ W_w, const float* __restrict__ W_b,
    const float* __restrict__ T_w, const float* __restrict__ T_b,
    const float* __restrict__ V, float* __restrict__ p_t,
    float* __restrict__ out, double* __restrict__ jpart) {
    __shared__ __align__(16) float ew[L_CNT * D_CNT];   // 24000 B
    __shared__ __align__(16) float vsh[D_CNT];
    __shared__ __align__(16) float zsh[D_CNT];
    __shared__ float axs[32], pts[32];
    __shared__ float4 red[8];
    const int tid = threadIdx.x;
    const float wb = W_b[tid >> 3];
    const float tb = (tid < D_CNT) ? T_b[tid] : 0.f;
    double jloc = 0.0;

    int r = blockIdx.x;
    float4 st[6];
    float4 vst = make_float4(0.f, 0.f, 0.f, 0.f);
    {   // prologue: stage first review
        const float4* src = (const float4*)(e_w + (size_t)r * 6000);
        #pragma unroll
        for (int i = 0; i < 6; ++i) {
            int idx = tid + 256 * i;
            if (idx < 1500) st[i] = src[idx];
        }
        if (tid < 50) vst = ((const float4*)(V + (size_t)r * D_CNT))[tid];
        float4* dst = (float4*)ew;
        #pragma unroll
        for (int i = 0; i < 6; ++i) {
            int idx = tid + 256 * i;
            if (idx < 1500) dst[idx] = st[i];
        }
        if (tid < 50) ((float4*)vsh)[tid] = vst;
    }
    __syncthreads();

    for (;;) {
        const int rn = r + GRID_MAIN;
        const bool have_next = (rn < R_CNT);
        if (have_next) {   // issue next review's loads NOW; consumed post-z_s
            const float4* src = (const float4*)(e_w + (size_t)rn * 6000);
            #pragma unroll
            for (int i = 0; i < 6; ++i) {
                int idx = tid + 256 * i;
                if (idx < 1500) st[i] = src[idx];
            }
            if (tid < 50) vst = ((const float4*)(V + (size_t)rn * D_CNT))[tid];
        }
        float zn0 = (tid < D_CNT) ? z_n[(size_t)(2 * r) * D_CNT + tid] : 0.f;
        float zn1 = (tid < D_CNT) ? z_n[(size_t)(2 * r + 1) * D_CNT + tid] : 0.f;

        // dx[l] = e_w[l,:].v  (bias cancels in softmax)
        if (tid < 240) {
            int l = tid >> 3, k = tid & 7;
            float p = 0.f;
            #pragma unroll
            for (int j = 0; j < 25; ++j)
                p = fmaf(ew[l * 200 + k + 8 * j], vsh[k + 8 * j], p);
            p += __shfl_xor(p, 1); p += __shfl_xor(p, 2); p += __shfl_xor(p, 4);
            if (k == 0) axs[l] = p;
        }
        __syncthreads();                               // B1

        if (tid < 64) {                                // softmax over L=30
            float v = (tid < L_CNT) ? axs[tid] : -3.0e38f;
            float m = v;
            #pragma unroll
            for (int o = 32; o >= 1; o >>= 1) m = fmaxf(m, __shfl_xor(m, o));
            float e = (tid < L_CNT) ? __expf(v - m) : 0.f;
            float s = e;
            #pragma unroll
            for (int o = 32; o >= 1; o >>= 1) s += __shfl_xor(s, o);
            if (tid < L_CNT) axs[tid] = e / s;
        }
        __syncthreads();                               // B2

        if (tid < D_CNT) {                             // z_s
            float z = 0.f;
            #pragma unroll
            for (int l = 0; l < L_CNT; ++l) z = fmaf(ew[l * 200 + tid], axs[l], z);
            zsh[tid] = z;
        }
        __syncthreads();                               // B3 (ew, vsh now free)

        if (have_next) {                               // stage write overlaps p_t
            float4* dst = (float4*)ew;
            #pragma unroll
            for (int i = 0; i < 6; ++i) {
                int idx = tid + 256 * i;
                if (idx < 1500) dst[idx] = st[i];
            }
            if (tid < 50) ((float4*)vsh)[tid] = vst;
        }
        {                                              // p_t
            int a = tid >> 3, k = tid & 7;
            float p = 0.f;
            #pragma unroll
            for (int j = 0; j < 25; ++j)
                p = fmaf(zsh[k + 8 * j], W_w[a * 200 + k + 8 * j], p);
            p += __shfl_xor(p, 1); p += __shfl_xor(p, 2); p += __shfl_xor(p, 4);
            if (k == 0) {
                float pt = p + wb;
                pts[a] = pt;
                p_t[(size_t)r * 32 + a] = pt;
            }
        }
        __syncthreads();                               // B4

        // r_s in-register + fused 7-channel loss reduce
        float rv = 0.f, zv = 0.f;
        if (tid < D_CNT) {
            rv = tb;
            const float4* tw = (const float4*)(T_w + tid * 32);
            #pragma unroll
            for (int q = 0; q < 8; ++q) {
                float4 t = tw[q];
                rv = fmaf(t.x, pts[4 * q + 0], rv);
                rv = fmaf(t.y, pts[4 * q + 1], rv);
                rv = fmaf(t.z, pts[4 * q + 2], rv);
                rv = fmaf(t.w, pts[4 * q + 3], rv);
            }
            zv = zsh[tid];
        }
        float4 Av = make_float4(rv * rv, rv * zv, zv * zv, zn0 * zn0);
        float4 Bv = make_float4(zn0 * rv, zn1 * zn1, zn1 * rv, 0.f);
        #pragma unroll
        for (int o = 32; o >= 1; o >>= 1) {
            Av.x += __shfl_xor(Av.x, o); Av.y += __shfl_xor(Av.y, o);
            Av.z += __shfl_xor(Av.z, o); Av.w += __shfl_xor(Av.w, o);
            Bv.x += __shfl_xor(Bv.x, o); Bv.y += __shfl_xor(Bv.y, o);
            Bv.z += __shfl_xor(Bv.z, o);
        }
        if ((tid & 63) == 0) { red[2 * (tid >> 6)] = Av; red[2 * (tid >> 6) + 1] = Bv; }
        __syncthreads();                               // B5
        if (tid == 0) {
            float rr = 0.f, rz = 0.f, zz = 0.f, n00 = 0.f, n0r = 0.f, n11 = 0.f, n1r = 0.f;
            #pragma unroll
            for (int i = 0; i < 4; ++i) {
                float4 a = red[2 * i], b = red[2 * i + 1];
                rr += a.x; rz += a.y; zz += a.z; n00 += a.w;
                n0r += b.x; n11 += b.y; n1r += b.z;
            }
            float nr = fmaxf(sqrtf(rr), 1e-12f);
            float nz = fmaxf(sqrtf(zz), 1e-12f);
            float c1  = rz  / (nr * nz);
            float c20 = n0r / (fmaxf(sqrtf(n00), 1e-12f) * nr);
            float c21 = n1r / (fmaxf(sqrtf(n11), 1e-12f) * nr);
            float l0 = fmaxf(0.f, 1.f - (c1 - c20));
            float l1 = fmaxf(0.f, 1.f - (c1 - c21));
            out[OUT_AB + 2 * r]     = l0;
            out[OUT_AB + 2 * r + 1] = l1;
            jloc += (double)l0 + (double)l1;
        }
        if (!have_next) break;
        r = rn;
    }
    if (tid == 0) jpart[blockIdx.x] = jloc;
}

// ---- K_scatter: user/item aspect segment sums via atomics ----
__global__ __launch_bounds__(256) void k_scatter(const int* __restrict__ u_idx,
                                                 const int* __restrict__ i_idx,
                                                 const float* __restrict__ u_val,
                                                 const float* __restrict__ i_val,
                                                 const float* __restrict__ p_t,
                                                 const int* __restrict__ mode,
                                                 float* __restrict__ out) {
    long long gid = (long long)blockIdx.x * 256 + threadIdx.x;
    const long long HALF = (long long)NNZ_CNT * 32;
    int is_item = gid >= HALF;
    long long rem = gid - (is_item ? HALF : 0);
    int k = (int)(rem >> 5), a = (int)(rem & 31);
    const int* idx = is_item ? i_idx : u_idx;
    const float* val = is_item ? i_val : u_val;
    int m64 = *mode;
    int row, col;
    if (m64) { row = idx[2 * k]; col = idx[2 * (NNZ_CNT + k)]; }
    else     { row = idx[k];     col = idx[NNZ_CNT + k]; }
    float v = p_t[col * 32 + a] * val[k];
    float* base = out + (is_item ? OUT_IA : OUT_UA);
    atomicAdd(&base[row * 32 + a], v);
}

// ---- K_fm: FM per-b terms; per-block partial of the global scalar S ----
__global__ __launch_bounds__(256) void k_fm(const float* __restrict__ out,
                                            const float* __restrict__ fc_w,
                                            const float* __restrict__ fc_b,
                                            const float* __restrict__ fm_V,
                                            float* __restrict__ fm_lin,
                                            double* __restrict__ spart) {
    __shared__ float parts[8];
    int tid = threadIdx.x;
    int a = tid & 31;
    int b = blockIdx.x * 8 + (tid >> 5);
    float ua = out[OUT_UA + b * 32 + a];
    float ia = out[OUT_IA + b * 32 + a];
    float oe = ua * ia;
    float oe2 = oe * oe;
    float lin = oe * fc_w[a];
    #pragma unroll
    for (int o = 1; o < 32; o <<= 1) lin += __shfl_xor(lin, o);
    float part = 0.f;
    #pragma unroll
    for (int j = 0; j < 10; j++) {
        float v = fm_V[a * 10 + j];
        float s1 = oe * v;
        float s2 = oe2 * v * v;
        #pragma unroll
        for (int o = 1; o < 32; o <<= 1) { s1 += __shfl_xor(s1, o); s2 += __shfl_xor(s2, o); }
        part += s1 * s1 - s2;
    }
    if (a == 0) {
        fm_lin[b] = lin + fc_b[0];
        parts[tid >> 5] = part;
    }
    __syncthreads();
    if (tid == 0) {
        float s = 0.f;
        #pragma unroll
        for (int i = 0; i < 8; ++i) s += parts[i];
        spart[blockIdx.x] = 0.5 * (double)s;
    }
}

// ---- K_pred: S = sum(spart); predictions + rating losses + rating_sum ----
__global__ __launch_bounds__(256) void k_pred(const float* __restrict__ label,
                                              const float* __restrict__ fm_lin,
                                              const double* __restrict__ spart,
                                              float* __restrict__ out,
                                              double* __restrict__ r_sum) {
    __shared__ double sred[4];
    __shared__ float4 red4[4];
    __shared__ float Ssh;
    int tid = threadIdx.x;
    double sl = spart[tid] + spart[tid + 256];
    #pragma unroll
    for (int o = 32; o >= 1; o >>= 1) sl += __shfl_xor(sl, o);
    if ((tid & 63) == 0) sred[tid >> 6] = sl;
    __syncthreads();
    if (tid == 0) Ssh = (float)(sred[0] + sred[1] + sred[2] + sred[3]);
    __syncthreads();
    float S = Ssh;
    int b = blockIdx.x * 256 + tid;
    float pred = fm_lin[b] + S + AVG_RATING;
    float d = pred - label[b];
    float rl = d * d;
    out[OUT_PRED + b] = pred;
    out[OUT_RL + b] = rl;
    float4 t = blk_reduce4(make_float4(rl, 0.f, 0.f, 0.f), red4);
    if (tid == 0) atomicAdd(r_sum, (double)t.x);
}

// ---- K_final: reduce jpart/upart, assemble scalar objective ----
__global__ __launch_bounds__(256) void k_final(const double* __restrict__ dbl,
                                               const double* __restrict__ jpart,
                                               const float* __restrict__ upart,
                                               float* __restrict__ out) {
    __shared__ double jred[4];
    __shared__ float ured[4];
    int tid = threadIdx.x;
    double j = 0.0;
    #pragma unroll
    for (int i = 0; i < 6; ++i) j += jpart[tid + 256 * i];
    float u = (tid < 32) ? upart[tid] : 0.f;
    #pragma unroll
    for (int o = 32; o >= 1; o >>= 1) { j += __shfl_xor(j, o); u += __shfl_xor(u, o); }
    if ((tid & 63) == 0) { jred[tid >> 6] = j; ured[tid >> 6] = u; }
    __syncthreads();
    if (tid == 0) {
        double J = (jred[0] + jred[1] + jred[2] + jred[3]) / (2.0 * R_CNT);
        double U = (double)(ured[0] + ured[1] + ured[2] + ured[3]) / 1024.0;
        double RL = dbl[2] / (double)B_CNT;
        out[OUT_OBJ] = (float)(RL + U + J);
    }
}

extern "C" void kernel_launch(void* const* d_in, const int* in_sizes, int n_in,
                              void* d_out, int out_size, void* d_ws, size_t ws_size,
                              hipStream_t stream) {
    const float* e_w   = (const float*)d_in[0];
    const float* y_s   = (const float*)d_in[1];
    const float* z_n   = (const float*)d_in[2];
    const float* label = (const float*)d_in[3];
    const float* u_val = (const float*)d_in[4];
    const float* i_val = (const float*)d_in[5];
    const float* M_w   = (const float*)d_in[6];
    const float* W_w   = (const float*)d_in[8];
    const float* W_b   = (const float*)d_in[9];
    const float* T_w   = (const float*)d_in[10];
    const float* T_b   = (const float*)d_in[11];
    const float* fc_w  = (const float*)d_in[12];
    const float* fc_b  = (const float*)d_in[13];
    const float* fm_V  = (const float*)d_in[14];
    const int*   u_idx = (const int*)d_in[15];
    const int*   i_idx = (const int*)d_in[16];

    float* out = (float*)d_out;
    char* ws = (char*)d_ws;
    double* dbl   = (double*)(ws + WS_DBL);
    int* mode     = (int*)(ws + WS_MODE);
    float* fm_lin = (float*)(ws + WS_FMLIN);
    float* p_t    = (float*)(ws + WS_PT);
    float* V      = (float*)(ws + WS_V);
    double* jpart = (double*)(ws + WS_JPART);
    double* spart = (double*)(ws + WS_SPART);
    float* upart  = (float*)(ws + WS_UPART);

    k_init<<<1024, 256, 0, stream>>>(out, dbl, mode, u_idx);
    k_vgemm<<<(R_CNT + 63) / 64, 256, 0, stream>>>(y_s, M_w, V);
    k_uloss<<<32, 256, 0, stream>>>(T_w, upart);
    k_main<<<GRID_MAIN, 256, 0, stream>>>(e_w, z_n, W_w, W_b, T_w, T_b,
                                          V, p_t, out, jpart);
    k_scatter<<<(2 * NNZ_CNT * 32) / 256, 256, 0, stream>>>(u_idx, i_idx, u_val, i_val,
                                                            p_t, mode, out);
    k_fm<<<B_CNT / 8, 256, 0, stream>>>(out, fc_w, fc_b, fm_V, fm_lin, spart);
    k_pred<<<B_CNT / 256, 256, 0, stream>>>(label, fm_lin, spart, out, &dbl[2]);
    k_final<<<1, 256, 0, stream>>>(dbl, jpart, upart, out);
}

// Round 7
// 330.374 us; speedup vs baseline: 1.7108x; 1.6676x over previous
//
#include <hip/hip_runtime.h>
#include <hip/hip_bf16.h>
#include <math.h>

#define R_CNT   20000
#define L_CNT   30
#define D_CNT   200
#define A_CNT   32
#define B_CNT   4096
#define NNZ_CNT 65536
#define AVG_RATING 3.8f

#define KA_GRID 768      // persistent attn blocks: 3/CU (LDS-bound)

// ---- d_out layout (floats) ----
#define OUT_OBJ  0
#define OUT_RL   1
#define OUT_AB   (1 + B_CNT)               // 4097
#define OUT_PRED (OUT_AB + 2*R_CNT)        // 44097
#define OUT_UA   (OUT_PRED + B_CNT)        // 48193
#define OUT_IA   (OUT_UA + B_CNT*A_CNT)    // 179265

// ---- ws layout (bytes) ----
#define WS_DBL    0         // double[4]: [2]=rating_sum
#define WS_MODE   32        // int (1 => indices are int64 in memory)
#define WS_FMLIN  64        // float[4096]
#define WS_PT     16448     // float[R*32]
#define WS_V      2576448   // float[R*200]; k_attn overwrites row r with z_s[r]
#define WS_WT     18576448  // float[200*32]  W transposed: W_t[d][a]
#define WS_TT     18602048  // float[32*200]  T transposed: T_t[a][d]
#define WS_JPART  18627648  // double[5000]
#define WS_SPART  18667648  // double[512]
#define WS_UPART  18671744  // float[32]

// Raw barrier + LDS drain (does NOT drain vmcnt -> keeps prefetch in flight)
#define BAR_LDS() do { asm volatile("s_waitcnt lgkmcnt(0)" ::: "memory"); \
                       __builtin_amdgcn_s_barrier(); \
                       __builtin_amdgcn_sched_barrier(0); } while (0)
// Tail barrier: wait the 7 stage loads (tolerate 1 pending z_s store)
#define BAR_TAIL() do { asm volatile("s_waitcnt vmcnt(1)" ::: "memory"); \
                        __builtin_amdgcn_s_barrier(); \
                        __builtin_amdgcn_sched_barrier(0); } while (0)

// Block-wide reduction of 4 channels across 256 threads (4 waves of 64).
__device__ __forceinline__ float4 blk_reduce4(float4 v, float4* scratch) {
    __syncthreads();
    #pragma unroll
    for (int o = 32; o >= 1; o >>= 1) {
        v.x += __shfl_xor(v.x, o);
        v.y += __shfl_xor(v.y, o);
        v.z += __shfl_xor(v.z, o);
        v.w += __shfl_xor(v.w, o);
    }
    int w = threadIdx.x >> 6;
    if ((threadIdx.x & 63) == 0) scratch[w] = v;
    __syncthreads();
    float4 t0 = scratch[0], t1 = scratch[1], t2 = scratch[2], t3 = scratch[3];
    return make_float4(t0.x + t1.x + t2.x + t3.x,
                       t0.y + t1.y + t2.y + t3.y,
                       t0.z + t1.z + t2.z + t3.z,
                       t0.w + t1.w + t2.w + t3.w);
}

// ---- K_init: zeros, index-dtype detect, transpose W_w and T_w ----
__global__ __launch_bounds__(256) void k_init(float* __restrict__ out,
                                              double* __restrict__ dbl,
                                              int* __restrict__ mode,
                                              const int* __restrict__ u_idx,
                                              const float* __restrict__ W_w,
                                              const float* __restrict__ T_w,
                                              float* __restrict__ W_t,
                                              float* __restrict__ T_t) {
    int gid = blockIdx.x * 256 + threadIdx.x;
    if (gid < 2 * B_CNT * A_CNT) out[OUT_UA + gid] = 0.f;
    if (gid < A_CNT * D_CNT) {
        int d = gid >> 5, a = gid & 31;          // W_t[d*32+a] = W_w[a][d]
        W_t[gid] = W_w[a * D_CNT + d];
        int a2 = gid / D_CNT, d2 = gid - a2 * D_CNT;  // T_t[a*200+d] = T_w[d][a]
        T_t[gid] = T_w[d2 * A_CNT + a2];
    }
    if (gid == 0) {
        dbl[0] = 0.0; dbl[1] = 0.0; dbl[2] = 0.0;
        int m = 1;
        for (int i = 1; i < 256; i += 2) if (u_idx[i] != 0) { m = 0; break; }
        *mode = m;
    }
}

// ---- K_uloss: orthogonality regularizer, one G-row per block ----
__global__ __launch_bounds__(256) void k_uloss(const float* __restrict__ T_w,
                                               float* __restrict__ upart) {
    __shared__ __align__(16) float Tsh[D_CNT * 32];
    __shared__ float tn[32];
    __shared__ float4 red4[4];
    int tid = threadIdx.x;
    for (int idx = tid; idx < 1600; idx += 256)
        ((float4*)Tsh)[idx] = ((const float4*)T_w)[idx];
    __syncthreads();
    int a = tid >> 3, k = tid & 7;
    float p = 0.f;
    #pragma unroll
    for (int j = 0; j < 25; ++j) { float t = Tsh[(k + 8*j)*32 + a]; p = fmaf(t, t, p); }
    p += __shfl_xor(p, 1); p += __shfl_xor(p, 2); p += __shfl_xor(p, 4);
    if (k == 0) tn[a] = fmaxf(sqrtf(p), 1e-12f);
    __syncthreads();
    const int i = blockIdx.x;
    float s = 0.f;
    #pragma unroll
    for (int j = 0; j < 25; ++j)
        s = fmaf(Tsh[(k + 8*j)*32 + i], Tsh[(k + 8*j)*32 + a], s);
    s += __shfl_xor(s, 1); s += __shfl_xor(s, 2); s += __shfl_xor(s, 4);
    float part = 0.f;
    if (k == 0) {
        float g = s / (tn[i] * tn[a]);
        float diff = g - ((i == a) ? 1.f : 0.f);
        part = diff * diff;
    }
    float4 tot = blk_reduce4(make_float4(part, 0.f, 0.f, 0.f), red4);
    if (tid == 0) upart[i] = tot.x;
}

// ---- K_vgemm: V = Y_s (R x 200) @ M_w (200 x 200) ----
__global__ __launch_bounds__(256) void k_vgemm(const float* __restrict__ y_s,
                                               const float* __restrict__ M_w,
                                               float* __restrict__ V) {
    __shared__ __align__(16) float Msh[25 * 260];
    __shared__ __align__(16) float Ysh[25 * 68];
    int tid = threadIdx.x;
    int r0 = blockIdx.x * 64;
    int dg = tid & 31, rg = tid >> 5;
    float acc[8][8];
    #pragma unroll
    for (int i = 0; i < 8; i++)
        #pragma unroll
        for (int j = 0; j < 8; j++) acc[i][j] = 0.f;

    for (int e0 = 0; e0 < D_CNT; e0 += 25) {
        __syncthreads();
        for (int idx = tid; idx < 25 * 256; idx += 256) {
            int ee = idx >> 8, d = idx & 255;
            Msh[ee * 260 + d] = (d < D_CNT) ? M_w[(e0 + ee) * D_CNT + d] : 0.f;
        }
        for (int idx = tid; idx < 25 * 64; idx += 256) {
            int rr = idx / 25, ee = idx - rr * 25;
            int row = r0 + rr;
            Ysh[ee * 68 + rr] = (row < R_CNT) ? y_s[row * D_CNT + e0 + ee] : 0.f;
        }
        __syncthreads();
        for (int ee = 0; ee < 25; ee++) {
            const float4 ya = *(const float4*)&Ysh[ee * 68 + rg * 8];
            const float4 yb = *(const float4*)&Ysh[ee * 68 + rg * 8 + 4];
            const float4 ma = *(const float4*)&Msh[ee * 260 + dg * 8];
            const float4 mb = *(const float4*)&Msh[ee * 260 + dg * 8 + 4];
            float ys[8] = {ya.x, ya.y, ya.z, ya.w, yb.x, yb.y, yb.z, yb.w};
            float ms[8] = {ma.x, ma.y, ma.z, ma.w, mb.x, mb.y, mb.z, mb.w};
            #pragma unroll
            for (int i = 0; i < 8; i++)
                #pragma unroll
                for (int j = 0; j < 8; j++)
                    acc[i][j] = fmaf(ys[i], ms[j], acc[i][j]);
        }
    }
    if (dg < 25) {
        #pragma unroll
        for (int i = 0; i < 8; i++) {
            int row = r0 + rg * 8 + i;
            if (row < R_CNT) {
                *(float4*)&V[row * D_CNT + dg * 8]     = make_float4(acc[i][0], acc[i][1], acc[i][2], acc[i][3]);
                *(float4*)&V[row * D_CNT + dg * 8 + 4] = make_float4(acc[i][4], acc[i][5], acc[i][6], acc[i][7]);
            }
        }
    }
}

// ---- stage one review: e_w row-block (24KB) + V row into LDS via global_load_lds
// Uniform 7 VMEM ops per wave: 6 x 16B e_w chunks + 1 x 4B V chunk.
__device__ __forceinline__ void stage_review(const float* __restrict__ ew_src,
                                             const float* __restrict__ v_src,
                                             float* ldsE, float* ldsV,
                                             int w, int lane) {
    #pragma unroll
    for (int i = 0; i < 6; ++i) {
        int c = w * 6 + i;                 // chunk 0..23, wave-uniform
        int f4 = c * 64 + lane;            // float4 index
        if (f4 > 1499) f4 = 1499;          // clamp tail (pad slots get dup data)
        __builtin_amdgcn_global_load_lds(
            (const __attribute__((address_space(1))) unsigned int*)(ew_src + (size_t)f4 * 4),
            (__attribute__((address_space(3))) unsigned int*)(ldsE + c * 256),
            16, 0, 0);
    }
    // V row: 256 floats (56-float over-read into ws scratch, unused)
    __builtin_amdgcn_global_load_lds(
        (const __attribute__((address_space(1))) unsigned int*)(v_src + w * 64 + lane),
        (__attribute__((address_space(3))) unsigned int*)(ldsV + w * 64),
        4, 0, 0);
}

// ---- K_attn: persistent, gload_lds double-buffered dx->softmax->z_s core ----
// z_s[r] overwrites V[r] in place (V row dead after its dx).
__global__ __launch_bounds__(256) void k_attn(const float* __restrict__ e_w,
                                              const float* __restrict__ V,
                                              float* __restrict__ zs) {
    __shared__ __align__(16) float bufE[2][6144];
    __shared__ __align__(16) float bufV[2][256];
    __shared__ float axs[32];
    const int tid = threadIdx.x;
    const int w = tid >> 6, lane = tid & 63;

    int r = blockIdx.x;
    stage_review(e_w + (size_t)r * 6000, V + (size_t)r * D_CNT,
                 bufE[0], bufV[0], w, lane);
    __syncthreads();   // prologue: full drain, buf0 ready
    int cur = 0;

    for (;;) {
        const int rn = r + KA_GRID;
        const bool have_next = (rn < R_CNT);
        if (have_next)
            stage_review(e_w + (size_t)rn * 6000, V + (size_t)rn * D_CNT,
                         bufE[cur ^ 1], bufV[cur ^ 1], w, lane);

        const float* ew = bufE[cur];
        const float* vsh = bufV[cur];

        // dx[l] = e_w[l,:].v  (M_b.y_s bias is constant over l -> cancels)
        if (tid < 240) {
            int l = tid >> 3, k = tid & 7;
            float p = 0.f;
            #pragma unroll
            for (int j = 0; j < 25; ++j)
                p = fmaf(ew[l * 200 + k + 8 * j], vsh[k + 8 * j], p);
            p += __shfl_xor(p, 1); p += __shfl_xor(p, 2); p += __shfl_xor(p, 4);
            if (k == 0) axs[l] = p;
        }
        BAR_LDS();                               // B1

        if (tid < 64) {                          // softmax over L=30
            float v = (tid < L_CNT) ? axs[tid] : -3.0e38f;
            float m = v;
            #pragma unroll
            for (int o = 32; o >= 1; o >>= 1) m = fmaxf(m, __shfl_xor(m, o));
            float e = (tid < L_CNT) ? __expf(v - m) : 0.f;
            float s = e;
            #pragma unroll
            for (int o = 32; o >= 1; o >>= 1) s += __shfl_xor(s, o);
            if (tid < L_CNT) axs[tid] = e / s;
        }
        BAR_LDS();                               // B2

        if (tid < D_CNT) {                       // z_s -> global (over V row)
            float z = 0.f;
            #pragma unroll
            for (int l = 0; l < L_CNT; ++l) z = fmaf(ew[l * 200 + tid], axs[l], z);
            zs[(size_t)r * D_CNT + tid] = z;
        }
        if (!have_next) break;
        BAR_TAIL();                              // reads done + next buf landed
        cur ^= 1; r = rn;
    }
}

// ---- K_pt: p_t = z_s @ W_w^T + W_b  (8 reviews/block, no reductions) ----
__global__ __launch_bounds__(256) void k_pt(const float* __restrict__ zs,
                                            const float* __restrict__ W_t,
                                            const float* __restrict__ W_b,
                                            float* __restrict__ p_t) {
    __shared__ __align__(16) float zsh[8 * 200];
    int tid = threadIdx.x;
    int r0 = blockIdx.x * 8;
    for (int i = tid; i < 400; i += 256)
        ((float4*)zsh)[i] = ((const float4*)(zs + (size_t)r0 * 200))[i];
    __syncthreads();
    int g = tid >> 5, a = tid & 31;
    float acc = W_b[a];
    const float4* z4 = (const float4*)&zsh[g * 200];
    #pragma unroll
    for (int d4 = 0; d4 < 50; ++d4) {
        float4 z = z4[d4];
        acc = fmaf(z.x, W_t[(d4 * 4 + 0) * 32 + a], acc);
        acc = fmaf(z.y, W_t[(d4 * 4 + 1) * 32 + a], acc);
        acc = fmaf(z.z, W_t[(d4 * 4 + 2) * 32 + a], acc);
        acc = fmaf(z.w, W_t[(d4 * 4 + 3) * 32 + a], acc);
    }
    p_t[(size_t)r0 * 32 + tid] = acc;
}

// ---- K_loss: wave-per-review r_s + cosine hinge losses ----
__global__ __launch_bounds__(256) void k_loss(const float* __restrict__ zs,
                                              const float* __restrict__ z_n,
                                              const float* __restrict__ p_t,
                                              const float* __restrict__ T_t,
                                              const float* __restrict__ T_b,
                                              float* __restrict__ out,
                                              double* __restrict__ jpart) {
    __shared__ double jred[4];
    int tid = threadIdx.x, w = tid >> 6, j = tid & 63;
    int r = blockIdx.x * 4 + w;
    float ptl = (j < 32) ? p_t[(size_t)r * 32 + j] : 0.f;
    float rs[4], zv[4], za[4], zb[4];
    #pragma unroll
    for (int s = 0; s < 4; ++s) {
        int d = j + 64 * s;
        bool ok = d < D_CNT;
        int dc = ok ? d : 0;
        rs[s] = ok ? T_b[dc] : 0.f;
        zv[s] = ok ? zs[(size_t)r * 200 + dc] : 0.f;
        za[s] = ok ? z_n[(size_t)(2 * r) * 200 + dc] : 0.f;
        zb[s] = ok ? z_n[(size_t)(2 * r + 1) * 200 + dc] : 0.f;
        if (!ok) { zv[s] = 0.f; za[s] = 0.f; zb[s] = 0.f; }
    }
    #pragma unroll
    for (int a = 0; a < 32; ++a) {
        float pa = __shfl(ptl, a);
        #pragma unroll
        for (int s = 0; s < 4; ++s) {
            int d = j + 64 * s;
            if (d < D_CNT) rs[s] = fmaf(pa, T_t[a * 200 + d], rs[s]);
        }
    }
    if (j + 192 >= D_CNT) rs[3] = 0.f;
    float rr = 0.f, rz = 0.f, zz = 0.f, n00 = 0.f, n0r = 0.f, n11 = 0.f, n1r = 0.f;
    #pragma unroll
    for (int s = 0; s < 4; ++s) {
        rr  += rs[s] * rs[s];  rz  += rs[s] * zv[s];  zz  += zv[s] * zv[s];
        n00 += za[s] * za[s];  n0r += za[s] * rs[s];
        n11 += zb[s] * zb[s];  n1r += zb[s] * rs[s];
    }
    #pragma unroll
    for (int o = 1; o < 64; o <<= 1) {
        rr  += __shfl_xor(rr, o);  rz  += __shfl_xor(rz, o);
        zz  += __shfl_xor(zz, o);  n00 += __shfl_xor(n00, o);
        n0r += __shfl_xor(n0r, o); n11 += __shfl_xor(n11, o);
        n1r += __shfl_xor(n1r, o);
    }
    if (j == 0) {
        float nr = fmaxf(sqrtf(rr), 1e-12f);
        float nz = fmaxf(sqrtf(zz), 1e-12f);
        float c1  = rz  / (nr * nz);
        float c20 = n0r / (fmaxf(sqrtf(n00), 1e-12f) * nr);
        float c21 = n1r / (fmaxf(sqrtf(n11), 1e-12f) * nr);
        float l0 = fmaxf(0.f, 1.f - (c1 - c20));
        float l1 = fmaxf(0.f, 1.f - (c1 - c21));
        out[OUT_AB + 2 * r]     = l0;
        out[OUT_AB + 2 * r + 1] = l1;
        jred[w] = (double)l0 + (double)l1;
    }
    __syncthreads();
    if (tid == 0) jpart[blockIdx.x] = jred[0] + jred[1] + jred[2] + jred[3];
}

// ---- K_scatter: user/item aspect segment sums via atomics ----
__global__ __launch_bounds__(256) void k_scatter(const int* __restrict__ u_idx,
                                                 const int* __restrict__ i_idx,
                                                 const float* __restrict__ u_val,
                                                 const float* __restrict__ i_val,
                                                 const float* __restrict__ p_t,
                                                 const int* __restrict__ mode,
                                                 float* __restrict__ out) {
    long long gid = (long long)blockIdx.x * 256 + threadIdx.x;
    const long long HALF = (long long)NNZ_CNT * 32;
    int is_item = gid >= HALF;
    long long rem = gid - (is_item ? HALF : 0);
    int k = (int)(rem >> 5), a = (int)(rem & 31);
    const int* idx = is_item ? i_idx : u_idx;
    const float* val = is_item ? i_val : u_val;
    int m64 = *mode;
    int row, col;
    if (m64) { row = idx[2 * k]; col = idx[2 * (NNZ_CNT + k)]; }
    else     { row = idx[k];     col = idx[NNZ_CNT + k]; }
    float v = p_t[col * 32 + a] * val[k];
    float* base = out + (is_item ? OUT_IA : OUT_UA);
    atomicAdd(&base[row * 32 + a], v);
}

// ---- K_fm: FM per-b terms; per-block partial of the global scalar S ----
__global__ __launch_bounds__(256) void k_fm(const float* __restrict__ out,
                                            const float* __restrict__ fc_w,
                                            const float* __restrict__ fc_b,
                                            const float* __restrict__ fm_V,
                                            float* __restrict__ fm_lin,
                                            double* __restrict__ spart) {
    __shared__ float parts[8];
    int tid = threadIdx.x;
    int a = tid & 31;
    int b = blockIdx.x * 8 + (tid >> 5);
    float ua = out[OUT_UA + b * 32 + a];
    float ia = out[OUT_IA + b * 32 + a];
    float oe = ua * ia;
    float oe2 = oe * oe;
    float lin = oe * fc_w[a];
    #pragma unroll
    for (int o = 1; o < 32; o <<= 1) lin += __shfl_xor(lin, o);
    float part = 0.f;
    #pragma unroll
    for (int j = 0; j < 10; j++) {
        float v = fm_V[a * 10 + j];
        float s1 = oe * v;
        float s2 = oe2 * v * v;
        #pragma unroll
        for (int o = 1; o < 32; o <<= 1) { s1 += __shfl_xor(s1, o); s2 += __shfl_xor(s2, o); }
        part += s1 * s1 - s2;
    }
    if (a == 0) {
        fm_lin[b] = lin + fc_b[0];
        parts[tid >> 5] = part;
    }
    __syncthreads();
    if (tid == 0) {
        float s = 0.f;
        #pragma unroll
        for (int i = 0; i < 8; ++i) s += parts[i];
        spart[blockIdx.x] = 0.5 * (double)s;
    }
}

// ---- K_pred: S = sum(spart); predictions + rating losses + rating_sum ----
__global__ __launch_bounds__(256) void k_pred(const float* __restrict__ label,
                                              const float* __restrict__ fm_lin,
                                              const double* __restrict__ spart,
                                              float* __restrict__ out,
                                              double* __restrict__ r_sum) {
    __shared__ double sred[4];
    __shared__ float4 red4[4];
    __shared__ float Ssh;
    int tid = threadIdx.x;
    double sl = spart[tid] + spart[tid + 256];
    #pragma unroll
    for (int o = 32; o >= 1; o >>= 1) sl += __shfl_xor(sl, o);
    if ((tid & 63) == 0) sred[tid >> 6] = sl;
    __syncthreads();
    if (tid == 0) Ssh = (float)(sred[0] + sred[1] + sred[2] + sred[3]);
    __syncthreads();
    float S = Ssh;
    int b = blockIdx.x * 256 + tid;
    float pred = fm_lin[b] + S + AVG_RATING;
    float d = pred - label[b];
    float rl = d * d;
    out[OUT_PRED + b] = pred;
    out[OUT_RL + b] = rl;
    float4 t = blk_reduce4(make_float4(rl, 0.f, 0.f, 0.f), red4);
    if (tid == 0) atomicAdd(r_sum, (double)t.x);
}

// ---- K_final: reduce jpart/upart, assemble scalar objective ----
__global__ __launch_bounds__(256) void k_final(const double* __restrict__ dbl,
                                               const double* __restrict__ jpart,
                                               const float* __restrict__ upart,
                                               float* __restrict__ out) {
    __shared__ double jred[4];
    __shared__ float ured[4];
    int tid = threadIdx.x;
    double j = 0.0;
    for (int i = tid; i < 5000; i += 256) j += jpart[i];
    float u = (tid < 32) ? upart[tid] : 0.f;
    #pragma unroll
    for (int o = 32; o >= 1; o >>= 1) { j += __shfl_xor(j, o); u += __shfl_xor(u, o); }
    if ((tid & 63) == 0) { jred[tid >> 6] = j; ured[tid >> 6] = u; }
    __syncthreads();
    if (tid == 0) {
        double J = (jred[0] + jred[1] + jred[2] + jred[3]) / (2.0 * R_CNT);
        double U = (double)(ured[0] + ured[1] + ured[2] + ured[3]) / 1024.0;
        double RL = dbl[2] / (double)B_CNT;
        out[OUT_OBJ] = (float)(RL + U + J);
    }
}

extern "C" void kernel_launch(void* const* d_in, const int* in_sizes, int n_in,
                              void* d_out, int out_size, void* d_ws, size_t ws_size,
                              hipStream_t stream) {
    const float* e_w   = (const float*)d_in[0];
    const float* y_s   = (const float*)d_in[1];
    const float* z_n   = (const float*)d_in[2];
    const float* label = (const float*)d_in[3];
    const float* u_val = (const float*)d_in[4];
    const float* i_val = (const float*)d_in[5];
    const float* M_w   = (const float*)d_in[6];
    const float* W_w   = (const float*)d_in[8];
    const float* W_b   = (const float*)d_in[9];
    const float* T_w   = (const float*)d_in[10];
    const float* T_b   = (const float*)d_in[11];
    const float* fc_w  = (const float*)d_in[12];
    const float* fc_b  = (const float*)d_in[13];
    const float* fm_V  = (const float*)d_in[14];
    const int*   u_idx = (const int*)d_in[15];
    const int*   i_idx = (const int*)d_in[16];

    float* out = (float*)d_out;
    char* ws = (char*)d_ws;
    double* dbl   = (double*)(ws + WS_DBL);
    int* mode     = (int*)(ws + WS_MODE);
    float* fm_lin = (float*)(ws + WS_FMLIN);
    float* p_t    = (float*)(ws + WS_PT);
    float* V      = (float*)(ws + WS_V);   // becomes z_s in place
    float* W_t    = (float*)(ws + WS_WT);
    float* T_t    = (float*)(ws + WS_TT);
    double* jpart = (double*)(ws + WS_JPART);
    double* spart = (double*)(ws + WS_SPART);
    float* upart  = (float*)(ws + WS_UPART);

    k_init<<<1024, 256, 0, stream>>>(out, dbl, mode, u_idx, W_w, T_w, W_t, T_t);
    k_vgemm<<<(R_CNT + 63) / 64, 256, 0, stream>>>(y_s, M_w, V);
    k_uloss<<<32, 256, 0, stream>>>(T_w, upart);
    k_attn<<<KA_GRID, 256, 0, stream>>>(e_w, V, V);
    k_pt<<<R_CNT / 8, 256, 0, stream>>>(V, W_t, W_b, p_t);
    k_loss<<<R_CNT / 4, 256, 0, stream>>>(V, z_n, p_t, T_t, T_b, out, jpart);
    k_scatter<<<(2 * NNZ_CNT * 32) / 256, 256, 0, stream>>>(u_idx, i_idx, u_val, i_val,
                                                            p_t, mode, out);
    k_fm<<<B_CNT / 8, 256, 0, stream>>>(out, fc_w, fc_b, fm_V, fm_lin, spart);
    k_pred<<<B_CNT / 256, 256, 0, stream>>>(label, fm_lin, spart, out, &dbl[2]);
    k_final<<<1, 256, 0, stream>>>(dbl, jpart, upart, out);
}

// Round 8
// 329.855 us; speedup vs baseline: 1.7135x; 1.0016x over previous
//
#include <hip/hip_runtime.h>
#include <hip/hip_bf16.h>
#include <math.h>

#define R_CNT   20000
#define L_CNT   30
#define D_CNT   200
#define A_CNT   32
#define B_CNT   4096
#define NNZ_CNT 65536
#define AVG_RATING 3.8f

#define KA_GRID 768      // persistent attn blocks: 3/CU (LDS-bound)

// ---- d_out layout (floats) ----
#define OUT_OBJ  0
#define OUT_RL   1
#define OUT_AB   (1 + B_CNT)               // 4097
#define OUT_PRED (OUT_AB + 2*R_CNT)        // 44097
#define OUT_UA   (OUT_PRED + B_CNT)        // 48193
#define OUT_IA   (OUT_UA + B_CNT*A_CNT)    // 179265

// ---- ws layout (bytes) ----
#define WS_DBL    0         // double[4]: [2]=rating_sum
#define WS_MODE   32        // int (1 => indices are int64 in memory)
#define WS_FMLIN  64        // float[4096]
#define WS_PT     16448     // float[R*32]
#define WS_V      2576448   // float[R*200]
#define WS_JPART  18627648  // double[KA_GRID]
#define WS_SPART  18667648  // double[512]
#define WS_UPART  18671744  // float[32]

// Raw barrier + LDS drain (does NOT drain vmcnt -> keeps prefetch in flight)
#define BAR_LDS() do { asm volatile("s_waitcnt lgkmcnt(0)" ::: "memory"); \
                       __builtin_amdgcn_s_barrier(); \
                       __builtin_amdgcn_sched_barrier(0); } while (0)
// Tail barrier: drain all but the newest store (stage loads are strictly
// older than the p_t/out stores issued after them -> stage fully landed).
#define BAR_TAIL() do { asm volatile("s_waitcnt vmcnt(1)" ::: "memory"); \
                        __builtin_amdgcn_s_barrier(); \
                        __builtin_amdgcn_sched_barrier(0); } while (0)

// Block-wide reduction of 4 channels across 256 threads (4 waves of 64).
__device__ __forceinline__ float4 blk_reduce4(float4 v, float4* scratch) {
    __syncthreads();
    #pragma unroll
    for (int o = 32; o >= 1; o >>= 1) {
        v.x += __shfl_xor(v.x, o);
        v.y += __shfl_xor(v.y, o);
        v.z += __shfl_xor(v.z, o);
        v.w += __shfl_xor(v.w, o);
    }
    int w = threadIdx.x >> 6;
    if ((threadIdx.x & 63) == 0) scratch[w] = v;
    __syncthreads();
    float4 t0 = scratch[0], t1 = scratch[1], t2 = scratch[2], t3 = scratch[3];
    return make_float4(t0.x + t1.x + t2.x + t3.x,
                       t0.y + t1.y + t2.y + t3.y,
                       t0.z + t1.z + t2.z + t3.z,
                       t0.w + t1.w + t2.w + t3.w);
}

// ---- K_init: zeros + index-dtype detect ----
__global__ __launch_bounds__(256) void k_init(float* __restrict__ out,
                                              double* __restrict__ dbl,
                                              int* __restrict__ mode,
                                              const int* __restrict__ u_idx) {
    int gid = blockIdx.x * 256 + threadIdx.x;
    if (gid < 2 * B_CNT * A_CNT) out[OUT_UA + gid] = 0.f;
    if (gid == 0) {
        dbl[0] = 0.0; dbl[1] = 0.0; dbl[2] = 0.0;
        int m = 1;
        for (int i = 1; i < 256; i += 2) if (u_idx[i] != 0) { m = 0; break; }
        *mode = m;
    }
}

// ---- K_uloss: orthogonality regularizer, one G-row per block ----
__global__ __launch_bounds__(256) void k_uloss(const float* __restrict__ T_w,
                                               float* __restrict__ upart) {
    __shared__ __align__(16) float Tsh[D_CNT * 32];
    __shared__ float tn[32];
    __shared__ float4 red4[4];
    int tid = threadIdx.x;
    for (int idx = tid; idx < 1600; idx += 256)
        ((float4*)Tsh)[idx] = ((const float4*)T_w)[idx];
    __syncthreads();
    int a = tid >> 3, k = tid & 7;
    float p = 0.f;
    #pragma unroll
    for (int j = 0; j < 25; ++j) { float t = Tsh[(k + 8*j)*32 + a]; p = fmaf(t, t, p); }
    p += __shfl_xor(p, 1); p += __shfl_xor(p, 2); p += __shfl_xor(p, 4);
    if (k == 0) tn[a] = fmaxf(sqrtf(p), 1e-12f);
    __syncthreads();
    const int i = blockIdx.x;
    float s = 0.f;
    #pragma unroll
    for (int j = 0; j < 25; ++j)
        s = fmaf(Tsh[(k + 8*j)*32 + i], Tsh[(k + 8*j)*32 + a], s);
    s += __shfl_xor(s, 1); s += __shfl_xor(s, 2); s += __shfl_xor(s, 4);
    float part = 0.f;
    if (k == 0) {
        float g = s / (tn[i] * tn[a]);
        float diff = g - ((i == a) ? 1.f : 0.f);
        part = diff * diff;
    }
    float4 tot = blk_reduce4(make_float4(part, 0.f, 0.f, 0.f), red4);
    if (tid == 0) upart[i] = tot.x;
}

// ---- K_vgemm: V = Y_s (R x 200) @ M_w (200 x 200) ----
__global__ __launch_bounds__(256) void k_vgemm(const float* __restrict__ y_s,
                                               const float* __restrict__ M_w,
                                               float* __restrict__ V) {
    __shared__ __align__(16) float Msh[25 * 260];
    __shared__ __align__(16) float Ysh[25 * 68];
    int tid = threadIdx.x;
    int r0 = blockIdx.x * 64;
    int dg = tid & 31, rg = tid >> 5;
    float acc[8][8];
    #pragma unroll
    for (int i = 0; i < 8; i++)
        #pragma unroll
        for (int j = 0; j < 8; j++) acc[i][j] = 0.f;

    for (int e0 = 0; e0 < D_CNT; e0 += 25) {
        __syncthreads();
        for (int idx = tid; idx < 25 * 256; idx += 256) {
            int ee = idx >> 8, d = idx & 255;
            Msh[ee * 260 + d] = (d < D_CNT) ? M_w[(e0 + ee) * D_CNT + d] : 0.f;
        }
        for (int idx = tid; idx < 25 * 64; idx += 256) {
            int rr = idx / 25, ee = idx - rr * 25;
            int row = r0 + rr;
            Ysh[ee * 68 + rr] = (row < R_CNT) ? y_s[row * D_CNT + e0 + ee] : 0.f;
        }
        __syncthreads();
        for (int ee = 0; ee < 25; ee++) {
            const float4 ya = *(const float4*)&Ysh[ee * 68 + rg * 8];
            const float4 yb = *(const float4*)&Ysh[ee * 68 + rg * 8 + 4];
            const float4 ma = *(const float4*)&Msh[ee * 260 + dg * 8];
            const float4 mb = *(const float4*)&Msh[ee * 260 + dg * 8 + 4];
            float ys[8] = {ya.x, ya.y, ya.z, ya.w, yb.x, yb.y, yb.z, yb.w};
            float ms[8] = {ma.x, ma.y, ma.z, ma.w, mb.x, mb.y, mb.z, mb.w};
            #pragma unroll
            for (int i = 0; i < 8; i++)
                #pragma unroll
                for (int j = 0; j < 8; j++)
                    acc[i][j] = fmaf(ys[i], ms[j], acc[i][j]);
        }
    }
    if (dg < 25) {
        #pragma unroll
        for (int i = 0; i < 8; i++) {
            int row = r0 + rg * 8 + i;
            if (row < R_CNT) {
                *(float4*)&V[row * D_CNT + dg * 8]     = make_float4(acc[i][0], acc[i][1], acc[i][2], acc[i][3]);
                *(float4*)&V[row * D_CNT + dg * 8 + 4] = make_float4(acc[i][4], acc[i][5], acc[i][6], acc[i][7]);
            }
        }
    }
}

// ---- stage one review: e_w row-block (24KB) + V row into LDS via global_load_lds
// Uniform 7 VMEM ops per wave: 6 x 16B e_w chunks + 1 x 4B V chunk.
__device__ __forceinline__ void stage_review(const float* __restrict__ ew_src,
                                             const float* __restrict__ v_src,
                                             float* ldsE, float* ldsV,
                                             int w, int lane) {
    #pragma unroll
    for (int i = 0; i < 6; ++i) {
        int c = w * 6 + i;                 // chunk 0..23, wave-uniform
        int f4 = c * 64 + lane;            // float4 index
        if (f4 > 1499) f4 = 1499;          // clamp tail (pad slots get dup data)
        __builtin_amdgcn_global_load_lds(
            (const __attribute__((address_space(1))) unsigned int*)(ew_src + (size_t)f4 * 4),
            (__attribute__((address_space(3))) unsigned int*)(ldsE + c * 256),
            16, 0, 0);
    }
    __builtin_amdgcn_global_load_lds(
        (const __attribute__((address_space(1))) unsigned int*)(v_src + w * 64 + lane),
        (__attribute__((address_space(3))) unsigned int*)(ldsV + w * 64),
        4, 0, 0);
}

// ---- K_attn: fused per-review pipeline (dx->softmax->z_s->p_t->loss) ----
// Persistent, gload_lds double-buffered. 5 raw barriers/review, counted-vmcnt
// tail. W_w/T_w read from global (L1/L2-hot, 25.6KB each, original layouts).
__global__ __launch_bounds__(256) void k_attn(const float* __restrict__ e_w,
                                              const float* __restrict__ V,
                                              const float* __restrict__ z_n,
                                              const float* __restrict__ W_w,
                                              const float* __restrict__ W_b,
                                              const float* __restrict__ T_w,
                                              const float* __restrict__ T_b,
                                              float* __restrict__ p_t,
                                              float* __restrict__ out,
                                              double* __restrict__ jpart) {
    __shared__ __align__(16) float bufE[2][6144];
    __shared__ __align__(16) float bufV[2][256];
    __shared__ __align__(16) float zsh[D_CNT];
    __shared__ float axs[32], pts[32];
    __shared__ float4 red[8];
    const int tid = threadIdx.x;
    const int w = tid >> 6, lane = tid & 63;
    const float wb = W_b[tid >> 3];
    const float tb = (tid < D_CNT) ? T_b[tid] : 0.f;
    double jloc = 0.0;

    int r = blockIdx.x;
    stage_review(e_w + (size_t)r * 6000, V + (size_t)r * D_CNT,
                 bufE[0], bufV[0], w, lane);
    __syncthreads();   // prologue: full drain, buf0 ready
    int cur = 0;

    for (;;) {
        const int rn = r + KA_GRID;
        const bool have_next = (rn < R_CNT);

        // z_n rows for CURRENT review (consumed in loss phase at the end)
        float zn0 = 0.f, zn1 = 0.f;
        if (tid < D_CNT) {
            zn0 = z_n[(size_t)(2 * r) * D_CNT + tid];
            zn1 = z_n[(size_t)(2 * r + 1) * D_CNT + tid];
        }
        if (have_next)
            stage_review(e_w + (size_t)rn * 6000, V + (size_t)rn * D_CNT,
                         bufE[cur ^ 1], bufV[cur ^ 1], w, lane);

        const float* ew = bufE[cur];
        const float* vsh = bufV[cur];

        // dx[l] = e_w[l,:].v  (M_b.y_s bias is constant over l -> cancels)
        if (tid < 240) {
            int l = tid >> 3, k = tid & 7;
            float p = 0.f;
            #pragma unroll
            for (int j = 0; j < 25; ++j)
                p = fmaf(ew[l * 200 + k + 8 * j], vsh[k + 8 * j], p);
            p += __shfl_xor(p, 1); p += __shfl_xor(p, 2); p += __shfl_xor(p, 4);
            if (k == 0) axs[l] = p;
        }
        BAR_LDS();                               // B1

        if (tid < 64) {                          // softmax over L=30
            float v = (tid < L_CNT) ? axs[tid] : -3.0e38f;
            float m = v;
            #pragma unroll
            for (int o = 32; o >= 1; o >>= 1) m = fmaxf(m, __shfl_xor(m, o));
            float e = (tid < L_CNT) ? __expf(v - m) : 0.f;
            float s = e;
            #pragma unroll
            for (int o = 32; o >= 1; o >>= 1) s += __shfl_xor(s, o);
            if (tid < L_CNT) axs[tid] = e / s;
        }
        BAR_LDS();                               // B2

        float zreg = 0.f;                        // z_s (register + LDS copy)
        if (tid < D_CNT) {
            #pragma unroll
            for (int l = 0; l < L_CNT; ++l)
                zreg = fmaf(ew[l * 200 + tid], axs[l], zreg);
            zsh[tid] = zreg;
        }
        BAR_LDS();                               // B3

        {                                        // p_t (8 lanes per aspect)
            int a = tid >> 3, k = tid & 7;
            float p = 0.f;
            #pragma unroll
            for (int j = 0; j < 25; ++j)
                p = fmaf(zsh[k + 8 * j], W_w[a * 200 + k + 8 * j], p);
            p += __shfl_xor(p, 1); p += __shfl_xor(p, 2); p += __shfl_xor(p, 4);
            if (k == 0) {
                float pt = p + wb;
                pts[a] = pt;
                p_t[(size_t)r * 32 + a] = pt;    // 1 store instr per wave
            }
        }
        BAR_LDS();                               // B4

        // r_s per-thread-d + fused 7-channel loss reduce
        float rv = 0.f;
        if (tid < D_CNT) {
            rv = tb;
            const float4* tw = (const float4*)(T_w + tid * 32);
            #pragma unroll
            for (int q = 0; q < 8; ++q) {
                float4 t = tw[q];
                rv = fmaf(t.x, pts[4 * q + 0], rv);
                rv = fmaf(t.y, pts[4 * q + 1], rv);
                rv = fmaf(t.z, pts[4 * q + 2], rv);
                rv = fmaf(t.w, pts[4 * q + 3], rv);
            }
        }
        float4 Av = make_float4(rv * rv, rv * zreg, zreg * zreg, zn0 * zn0);
        float4 Bv = make_float4(zn0 * rv, zn1 * zn1, zn1 * rv, 0.f);
        #pragma unroll
        for (int o = 32; o >= 1; o >>= 1) {
            Av.x += __shfl_xor(Av.x, o); Av.y += __shfl_xor(Av.y, o);
            Av.z += __shfl_xor(Av.z, o); Av.w += __shfl_xor(Av.w, o);
            Bv.x += __shfl_xor(Bv.x, o); Bv.y += __shfl_xor(Bv.y, o);
            Bv.z += __shfl_xor(Bv.z, o);
        }
        if ((tid & 63) == 0) { red[2 * w] = Av; red[2 * w + 1] = Bv; }
        BAR_LDS();                               // B5
        if (tid == 0) {
            float rr = 0.f, rz = 0.f, zz = 0.f, n00 = 0.f, n0r = 0.f, n11 = 0.f, n1r = 0.f;
            #pragma unroll
            for (int i = 0; i < 4; ++i) {
                float4 a = red[2 * i], b = red[2 * i + 1];
                rr += a.x; rz += a.y; zz += a.z; n00 += a.w;
                n0r += b.x; n11 += b.y; n1r += b.z;
            }
            float nr = fmaxf(sqrtf(rr), 1e-12f);
            float nz = fmaxf(sqrtf(zz), 1e-12f);
            float c1  = rz  / (nr * nz);
            float c20 = n0r / (fmaxf(sqrtf(n00), 1e-12f) * nr);
            float c21 = n1r / (fmaxf(sqrtf(n11), 1e-12f) * nr);
            float l0 = fmaxf(0.f, 1.f - (c1 - c20));
            float l1 = fmaxf(0.f, 1.f - (c1 - c21));
            out[OUT_AB + 2 * r]     = l0;
            out[OUT_AB + 2 * r + 1] = l1;
            jloc += (double)l0 + (double)l1;
        }
        if (!have_next) break;
        BAR_TAIL();                              // reads done + next buf landed
        cur ^= 1; r = rn;
    }
    if (tid == 0) jpart[blockIdx.x] = jloc;
}

// ---- K_scatter: user/item aspect segment sums via atomics ----
__global__ __launch_bounds__(256) void k_scatter(const int* __restrict__ u_idx,
                                                 const int* __restrict__ i_idx,
                                                 const float* __restrict__ u_val,
                                                 const float* __restrict__ i_val,
                                                 const float* __restrict__ p_t,
                                                 const int* __restrict__ mode,
                                                 float* __restrict__ out) {
    long long gid = (long long)blockIdx.x * 256 + threadIdx.x;
    const long long HALF = (long long)NNZ_CNT * 32;
    int is_item = gid >= HALF;
    long long rem = gid - (is_item ? HALF : 0);
    int k = (int)(rem >> 5), a = (int)(rem & 31);
    const int* idx = is_item ? i_idx : u_idx;
    const float* val = is_item ? i_val : u_val;
    int m64 = *mode;
    int row, col;
    if (m64) { row = idx[2 * k]; col = idx[2 * (NNZ_CNT + k)]; }
    else     { row = idx[k];     col = idx[NNZ_CNT + k]; }
    float v = p_t[col * 32 + a] * val[k];
    float* base = out + (is_item ? OUT_IA : OUT_UA);
    atomicAdd(&base[row * 32 + a], v);
}

// ---- K_fm: FM per-b terms; per-block partial of the global scalar S ----
__global__ __launch_bounds__(256) void k_fm(const float* __restrict__ out,
                                            const float* __restrict__ fc_w,
                                            const float* __restrict__ fc_b,
                                            const float* __restrict__ fm_V,
                                            float* __restrict__ fm_lin,
                                            double* __restrict__ spart) {
    __shared__ float parts[8];
    int tid = threadIdx.x;
    int a = tid & 31;
    int b = blockIdx.x * 8 + (tid >> 5);
    float ua = out[OUT_UA + b * 32 + a];
    float ia = out[OUT_IA + b * 32 + a];
    float oe = ua * ia;
    float oe2 = oe * oe;
    float lin = oe * fc_w[a];
    #pragma unroll
    for (int o = 1; o < 32; o <<= 1) lin += __shfl_xor(lin, o);
    float part = 0.f;
    #pragma unroll
    for (int j = 0; j < 10; j++) {
        float v = fm_V[a * 10 + j];
        float s1 = oe * v;
        float s2 = oe2 * v * v;
        #pragma unroll
        for (int o = 1; o < 32; o <<= 1) { s1 += __shfl_xor(s1, o); s2 += __shfl_xor(s2, o); }
        part += s1 * s1 - s2;
    }
    if (a == 0) {
        fm_lin[b] = lin + fc_b[0];
        parts[tid >> 5] = part;
    }
    __syncthreads();
    if (tid == 0) {
        float s = 0.f;
        #pragma unroll
        for (int i = 0; i < 8; ++i) s += parts[i];
        spart[blockIdx.x] = 0.5 * (double)s;
    }
}

// ---- K_pred: S = sum(spart); predictions + rating losses + rating_sum ----
__global__ __launch_bounds__(256) void k_pred(const float* __restrict__ label,
                                              const float* __restrict__ fm_lin,
                                              const double* __restrict__ spart,
                                              float* __restrict__ out,
                                              double* __restrict__ r_sum) {
    __shared__ double sred[4];
    __shared__ float4 red4[4];
    __shared__ float Ssh;
    int tid = threadIdx.x;
    double sl = spart[tid] + spart[tid + 256];
    #pragma unroll
    for (int o = 32; o >= 1; o >>= 1) sl += __shfl_xor(sl, o);
    if ((tid & 63) == 0) sred[tid >> 6] = sl;
    __syncthreads();
    if (tid == 0) Ssh = (float)(sred[0] + sred[1] + sred[2] + sred[3]);
    __syncthreads();
    float S = Ssh;
    int b = blockIdx.x * 256 + tid;
    float pred = fm_lin[b] + S + AVG_RATING;
    float d = pred - label[b];
    float rl = d * d;
    out[OUT_PRED + b] = pred;
    out[OUT_RL + b] = rl;
    float4 t = blk_reduce4(make_float4(rl, 0.f, 0.f, 0.f), red4);
    if (tid == 0) atomicAdd(r_sum, (double)t.x);
}

// ---- K_final: reduce jpart/upart, assemble scalar objective ----
__global__ __launch_bounds__(256) void k_final(const double* __restrict__ dbl,
                                               const double* __restrict__ jpart,
                                               const float* __restrict__ upart,
                                               float* __restrict__ out) {
    __shared__ double jred[4];
    __shared__ float ured[4];
    int tid = threadIdx.x;
    double j = 0.0;
    for (int i = tid; i < KA_GRID; i += 256) j += jpart[i];
    float u = (tid < 32) ? upart[tid] : 0.f;
    #pragma unroll
    for (int o = 32; o >= 1; o >>= 1) { j += __shfl_xor(j, o); u += __shfl_xor(u, o); }
    if ((tid & 63) == 0) { jred[tid >> 6] = j; ured[tid >> 6] = u; }
    __syncthreads();
    if (tid == 0) {
        double J = (jred[0] + jred[1] + jred[2] + jred[3]) / (2.0 * R_CNT);
        double U = (double)(ured[0] + ured[1] + ured[2] + ured[3]) / 1024.0;
        double RL = dbl[2] / (double)B_CNT;
        out[OUT_OBJ] = (float)(RL + U + J);
    }
}

extern "C" void kernel_launch(void* const* d_in, const int* in_sizes, int n_in,
                              void* d_out, int out_size, void* d_ws, size_t ws_size,
                              hipStream_t stream) {
    const float* e_w   = (const float*)d_in[0];
    const float* y_s   = (const float*)d_in[1];
    const float* z_n   = (const float*)d_in[2];
    const float* label = (const float*)d_in[3];
    const float* u_val = (const float*)d_in[4];
    const float* i_val = (const float*)d_in[5];
    const float* M_w   = (const float*)d_in[6];
    const float* W_w   = (const float*)d_in[8];
    const float* W_b   = (const float*)d_in[9];
    const float* T_w   = (const float*)d_in[10];
    const float* T_b   = (const float*)d_in[11];
    const float* fc_w  = (const float*)d_in[12];
    const float* fc_b  = (const float*)d_in[13];
    const float* fm_V  = (const float*)d_in[14];
    const int*   u_idx = (const int*)d_in[15];
    const int*   i_idx = (const int*)d_in[16];

    float* out = (float*)d_out;
    char* ws = (char*)d_ws;
    double* dbl   = (double*)(ws + WS_DBL);
    int* mode     = (int*)(ws + WS_MODE);
    float* fm_lin = (float*)(ws + WS_FMLIN);
    float* p_t    = (float*)(ws + WS_PT);
    float* V      = (float*)(ws + WS_V);
    double* jpart = (double*)(ws + WS_JPART);
    double* spart = (double*)(ws + WS_SPART);
    float* upart  = (float*)(ws + WS_UPART);

    k_init<<<1024, 256, 0, stream>>>(out, dbl, mode, u_idx);
    k_vgemm<<<(R_CNT + 63) / 64, 256, 0, stream>>>(y_s, M_w, V);
    k_uloss<<<32, 256, 0, stream>>>(T_w, upart);
    k_attn<<<KA_GRID, 256, 0, stream>>>(e_w, V, z_n, W_w, W_b, T_w, T_b,
                                        p_t, out, jpart);
    k_scatter<<<(2 * NNZ_CNT * 32) / 256, 256, 0, stream>>>(u_idx, i_idx, u_val, i_val,
                                                            p_t, mode, out);
    k_fm<<<B_CNT / 8, 256, 0, stream>>>(out, fc_w, fc_b, fm_V, fm_lin, spart);
    k_pred<<<B_CNT / 256, 256, 0, stream>>>(label, fm_lin, spart, out, &dbl[2]);
    k_final<<<1, 256, 0, stream>>>(dbl, jpart, upart, out);
}